// Round 13
// baseline (219.851 us; speedup 1.0000x reference)
//
#include <hip/hip_runtime.h>

#define C_IN   64
#define C_OUT  128
#define Himg   128
#define Wimg   128
#define HW     (Himg * Wimg)
#define TROWS  16
#define TCOLS  32
#define HROWS  18   // TROWS+2
#define HCOLS  34   // TCOLS+2
#define XCELLS (HROWS * HCOLS)   // 612
#define XKSTR  (XCELLS * 16)     // 9792 B per kidx row
#define WS_COH 73728             // 9 taps * 8 kidx * 64 co * 16 B
#define NINST  (XCELLS * 8)      // 4896 cell-instances per tile

typedef __bf16 bf16x8 __attribute__((ext_vector_type(8)));
typedef float  f32x16 __attribute__((ext_vector_type(16)));

__device__ __forceinline__ unsigned int pack2(float a, float b) {
  union { __bf16 h; unsigned short s; } ua, ub;
  ua.h = (__bf16)a; ub.h = (__bf16)b;
  return (unsigned int)ua.s | ((unsigned int)ub.s << 16);
}

__device__ __forceinline__ void gload_lds16(const void* g, void* l) {
  __builtin_amdgcn_global_load_lds((const __attribute__((address_space(1))) void*)g,
                                   (__attribute__((address_space(3))) void*)l, 16, 0, 0);
}

// fp32 W[co][c][3][3] -> bf16 wt, [coh][tap][kidx][co64][ch8] 16B cells (R12 layout, verified)
__global__ void wt_transform(const float* __restrict__ w, unsigned short* __restrict__ wt) {
  const int idx = blockIdx.x * 256 + threadIdx.x;
  if (idx >= 9 * C_OUT * C_IN) return;
  const int c   = idx & 63;
  const int co  = (idx >> 6) & 127;
  const int tap = idx >> 13;
  const int ky = tap / 3, kx = tap % 3;
  const float f = w[((co * C_IN + c) * 3 + ky) * 3 + kx];
  union { __bf16 h; unsigned short s; } u; u.h = (__bf16)f;
  const int coh = co >> 6, col = co & 63;
  wt[(((coh * 9 + tap) * 8) + (c >> 3)) * 512 + col * 8 + (c & 7)] = u.s;
}

__global__ __launch_bounds__(512, 1)
void conv_mfma(const float* __restrict__ xin, const unsigned short* __restrict__ wt,
               const float* __restrict__ bias, float* __restrict__ out) {
  __shared__ __align__(16) unsigned char Xs[8 * XKSTR];   // 78336
  __shared__ __align__(16) unsigned char Ws[WS_COH];      // 73728  (total 152064)

  const int tid = threadIdx.x;
  const int bid = blockIdx.x;            // 256 blocks, 1/CU
  const int xcd = bid & 7;
  const int k   = bid >> 3;              // 0..31
  const int coh = k & 1;
  const int strip = xcd * 16 + (k >> 1); // 0..127; coh-pair shares XCD -> L2 X reuse

  const int lane = tid & 63;
  const int wv   = tid >> 6;   // 0..7: row-pair
  const int lpx  = lane & 31;
  const int lkh  = lane >> 5;

  // ---- Ws DMA: entire coh weight slice, once per block ----
  {
    const unsigned short* s0 = wt + coh * 36864 + tid * 8;
    #pragma unroll
    for (int j = 0; j < 9; ++j)
      gload_lds16(s0 + j * 4096, &Ws[tid * 16 + j * 8192]);
  }

  float4 bq[2][4];
  #pragma unroll
  for (int mf = 0; mf < 2; ++mf)
    #pragma unroll
    for (int rq = 0; rq < 4; ++rq)
      bq[mf][rq] = *(const float4*)(bias + coh * 64 + mf * 32 + rq * 8 + lkh * 4);

  uint4 xc[10];   // packed staged cells (it = 0..9; it==9 only for tid<288)

  auto LOADX = [&](int img, int gy0, int gx0) {
    #pragma unroll
    for (int it = 0; it < 10; ++it) {
      const int inst = it * 512 + tid;
      if (it == 9 && tid >= NINST - 9 * 512) continue;
      const int kg   = inst / XCELLS;
      const int cell = inst - kg * XCELLS;
      const int row  = cell / HCOLS;
      const int col  = cell - row * HCOLS;
      const int gy = gy0 - 1 + row;
      const int gx = gx0 - 1 + col;
      float f[8] = {0.f, 0.f, 0.f, 0.f, 0.f, 0.f, 0.f, 0.f};
      if (gy >= 0 && gy < Himg && gx >= 0 && gx < Wimg) {
        const float* p = xin + ((size_t)img * C_IN + kg * 8) * HW + (size_t)gy * Wimg + gx;
        #pragma unroll
        for (int ch = 0; ch < 8; ++ch) f[ch] = p[(size_t)ch * HW];
      }
      xc[it].x = pack2(f[0], f[1]); xc[it].y = pack2(f[2], f[3]);
      xc[it].z = pack2(f[4], f[5]); xc[it].w = pack2(f[6], f[7]);
    }
  };

  auto WRITEX = [&]() {
    #pragma unroll
    for (int it = 0; it < 10; ++it) {
      const int inst = it * 512 + tid;
      if (it == 9 && tid >= NINST - 9 * 512) continue;
      const int kg   = inst / XCELLS;
      const int cell = inst - kg * XCELLS;
      *(uint4*)(&Xs[kg * XKSTR + cell * 16]) = xc[it];
    }
  };

  // tile index decode: ts in [strip*9, strip*9+9); 32 tiles/img, ty fastest (vertical strips)
  auto TDEC = [&](int ts, int& img, int& gy0, int& gx0) {
    img = ts >> 5;
    const int rem = ts & 31;
    gy0 = (rem & 7) * TROWS;
    gx0 = (rem >> 3) * TCOLS;
  };

  // ---- prologue: stage tile 0 ----
  {
    int img, gy0, gx0;
    TDEC(strip * 9, img, gy0, gx0);
    LOADX(img, gy0, gx0);
    WRITEX();
  }
  __syncthreads();   // drains Ws DMA + Xs ds_writes

  f32x16 acc[2][2];
  #pragma unroll
  for (int mf = 0; mf < 2; ++mf)
    #pragma unroll
    for (int nf = 0; nf < 2; ++nf)
      acc[mf][nf] = (f32x16)(0.f);

  #pragma unroll 1
  for (int i = 0; i < 9; ++i) {
    int img, gy0, gx0;
    TDEC(strip * 9 + i, img, gy0, gx0);

    if (i < 8) {   // T14: issue next tile's loads; land during compute below
      int nimg, ngy0, ngx0;
      TDEC(strip * 9 + i + 1, nimg, ngy0, ngx0);
      LOADX(nimg, ngy0, ngx0);
    }

    // ---- compute: 9 taps, acc[2][2] = 64co x 64px per wave ----
    #pragma unroll
    for (int t = 0; t < 9; ++t) {
      const int dy = (t >= 6) ? 2 : (t >= 3 ? 1 : 0);
      const int dx = t - dy * 3;
      int boff[2];
      #pragma unroll
      for (int nf = 0; nf < 2; ++nf)
        boff[nf] = ((wv * 2 + nf + dy) * HCOLS + dx + lpx) * 16;
      const int aoff = t * 8192 + lkh * 1024 + lpx * 16;
      #pragma unroll
      for (int ks = 0; ks < 4; ++ks) {
        bf16x8 A0 = *(const bf16x8*)&Ws[aoff + ks * 2048];
        bf16x8 A1 = *(const bf16x8*)&Ws[aoff + ks * 2048 + 512];
        bf16x8 B0 = *(const bf16x8*)&Xs[boff[0] + (ks * 2 + lkh) * XKSTR];
        bf16x8 B1 = *(const bf16x8*)&Xs[boff[1] + (ks * 2 + lkh) * XKSTR];
        __builtin_amdgcn_s_setprio(1);
        acc[0][0] = __builtin_amdgcn_mfma_f32_32x32x16_bf16(A0, B0, acc[0][0], 0, 0, 0);
        acc[0][1] = __builtin_amdgcn_mfma_f32_32x32x16_bf16(A0, B1, acc[0][1], 0, 0, 0);
        acc[1][0] = __builtin_amdgcn_mfma_f32_32x32x16_bf16(A1, B0, acc[1][0], 0, 0, 0);
        acc[1][1] = __builtin_amdgcn_mfma_f32_32x32x16_bf16(A1, B1, acc[1][1], 0, 0, 0);
        __builtin_amdgcn_s_setprio(0);
      }
    }

    // ---- stores: issued, NOT drained (overlap next tile) ----
    #pragma unroll
    for (int nf = 0; nf < 2; ++nf) {
      const int y = gy0 + wv * 2 + nf;
      float* op = out + (size_t)img * C_OUT * HW + (size_t)y * Wimg + gx0 + lpx;
      #pragma unroll
      for (int mf = 0; mf < 2; ++mf) {
        #pragma unroll
        for (int r = 0; r < 16; ++r) {
          const int co = coh * 64 + mf * 32 + (r & 3) + 8 * (r >> 2) + lkh * 4;
          op[(size_t)co * HW] = acc[mf][nf][r] + ((const float*)&bq[mf][r >> 2])[r & 3];
        }
      }
    }
    #pragma unroll
    for (int mf = 0; mf < 2; ++mf)
      #pragma unroll
      for (int nf = 0; nf < 2; ++nf)
        acc[mf][nf] = (f32x16)(0.f);

    if (i < 8) {
      // all waves done reading Xs (lgkm only — global stores stay in flight)
      asm volatile("s_waitcnt lgkmcnt(0)" ::: "memory");
      __builtin_amdgcn_s_barrier();
      __builtin_amdgcn_sched_barrier(0);
      WRITEX();    // compiler inserts counted vmcnt for xc load deps
      asm volatile("s_waitcnt lgkmcnt(0)" ::: "memory");
      __builtin_amdgcn_s_barrier();
      __builtin_amdgcn_sched_barrier(0);
    }
  }
}

extern "C" void kernel_launch(void* const* d_in, const int* in_sizes, int n_in,
                              void* d_out, int out_size, void* d_ws, size_t ws_size,
                              hipStream_t stream) {
  const float* x    = (const float*)d_in[0];
  const float* w    = (const float*)d_in[1];
  const float* bias = (const float*)d_in[2];
  float* out = (float*)d_out;
  unsigned short* wt = (unsigned short*)d_ws;  // 147456 B

  wt_transform<<<(9 * C_OUT * C_IN + 255) / 256, 256, 0, stream>>>(w, wt);

  conv_mfma<<<dim3(256), 512, 0, stream>>>(x, wt, bias, out);
}

// Round 14
// 144.733 us; speedup vs baseline: 1.5190x; 1.5190x over previous
//
#include <hip/hip_runtime.h>

#define C_IN   64
#define C_OUT  128
#define Himg   128
#define Wimg   128
#define HW     (Himg * Wimg)
#define HCOLS  34
#define XKSTR  5440            // 340 cells * 16 B per kidx row
#define WS_COH 73728           // 9 taps * 8 kidx * 64 co * 16 B

typedef __bf16 bf16x8 __attribute__((ext_vector_type(8)));
typedef float  f32x16 __attribute__((ext_vector_type(16)));

__device__ __forceinline__ unsigned int pack2(float a, float b) {
  union { __bf16 h; unsigned short s; } ua, ub;
  ua.h = (__bf16)a; ub.h = (__bf16)b;
  return (unsigned int)ua.s | ((unsigned int)ub.s << 16);
}

__device__ __forceinline__ void gload_lds16(const void* g, void* l) {
  __builtin_amdgcn_global_load_lds((const __attribute__((address_space(1))) void*)g,
                                   (__attribute__((address_space(3))) void*)l, 16, 0, 0);
}

// fp32 W[co][c][3][3] -> bf16 wt, [coh][tap][kidx][co64][ch8] 16B cells (verified R12)
__global__ void wt_transform(const float* __restrict__ w, unsigned short* __restrict__ wt) {
  const int idx = blockIdx.x * 256 + threadIdx.x;
  if (idx >= 9 * C_OUT * C_IN) return;
  const int c   = idx & 63;
  const int co  = (idx >> 6) & 127;
  const int tap = idx >> 13;
  const int ky = tap / 3, kx = tap % 3;
  const float f = w[((co * C_IN + c) * 3 + ky) * 3 + kx];
  union { __bf16 h; unsigned short s; } u; u.h = (__bf16)f;
  const int coh = co >> 6, col = co & 63;
  wt[(((coh * 9 + tap) * 8) + (c >> 3)) * 512 + col * 8 + (c & 7)] = u.s;
}

__global__ __launch_bounds__(512, 1)
void conv_mfma(const float* __restrict__ xin, const unsigned short* __restrict__ wt,
               const float* __restrict__ bias, float* __restrict__ out) {
  __shared__ __align__(16) unsigned char Xs[2][8 * XKSTR];  // 2*43520 ping-pong
  __shared__ __align__(16) unsigned char Ws[WS_COH];        // 73728 (total 160768)

  const int tid = threadIdx.x;
  const int bid = blockIdx.x;          // 512 blocks
  const int xcd = bid & 7;
  const int bi  = bid >> 3;            // 0..63
  const int coh = bi & 1;
  const int s   = xcd * 32 + (bi >> 1);  // 0..255: 9-tile strip id

  const int lane = tid & 63;
  const int wv   = tid >> 6;   // 0..7
  const int lpx  = lane & 31;
  const int lkh  = lane >> 5;
  const int wm   = wv & 1;     // co 32-half within coh slice
  const int wn   = wv >> 1;    // 0..3: rows 2wn, 2wn+1

  // staging role constants
  const int xi = tid & 31;            // px column
  const int kg = (tid >> 5) & 7;      // kidx
  const int hf = tid >> 8;            // row half: rows hf*5..hf*5+4
  const int hside = (tid >= 80) ? 1 : 0;      // halo (threads 0..159)
  const int hrr   = (tid - hside * 80) >> 3;  // halo row 0..9
  const int hkg   = tid & 7;

  // ---- Ws DMA: entire coh weight slice, once per block ----
  {
    const unsigned short* s0 = wt + coh * 36864 + tid * 8;
    #pragma unroll
    for (int j = 0; j < 9; ++j)
      gload_lds16(s0 + j * 4096, &Ws[tid * 16 + j * 8192]);
  }

  float4 bq[4];
  #pragma unroll
  for (int rq = 0; rq < 4; ++rq)
    bq[rq] = *(const float4*)(bias + coh * 64 + wm * 32 + rq * 8 + lkh * 4);

  float xr[5][8];
  float hr[8];

  auto LOADX = [&](int img, int gy0, int gx0) {
    const float* pb = xin + ((size_t)img * C_IN + kg * 8) * HW + gx0 + xi;
    #pragma unroll
    for (int j = 0; j < 5; ++j) {
      const int gy = gy0 - 1 + hf * 5 + j;
      if (gy >= 0 && gy < Himg) {
        const float* p = pb + (size_t)gy * Wimg;
        #pragma unroll
        for (int ch = 0; ch < 8; ++ch) xr[j][ch] = p[(size_t)ch * HW];
      } else {
        #pragma unroll
        for (int ch = 0; ch < 8; ++ch) xr[j][ch] = 0.f;
      }
    }
    if (tid < 160) {
      const int gx = hside ? gx0 + 32 : gx0 - 1;
      const int gy = gy0 - 1 + hrr;
      if (gy >= 0 && gy < Himg && gx >= 0 && gx < Wimg) {
        const float* p = xin + ((size_t)img * C_IN + hkg * 8) * HW + (size_t)gy * Wimg + gx;
        #pragma unroll
        for (int ch = 0; ch < 8; ++ch) hr[ch] = p[(size_t)ch * HW];
      } else {
        #pragma unroll
        for (int ch = 0; ch < 8; ++ch) hr[ch] = 0.f;
      }
    }
  };

  auto WRITEX = [&](int b) {
    #pragma unroll
    for (int j = 0; j < 5; ++j) {
      uint4 cell;
      cell.x = pack2(xr[j][0], xr[j][1]); cell.y = pack2(xr[j][2], xr[j][3]);
      cell.z = pack2(xr[j][4], xr[j][5]); cell.w = pack2(xr[j][6], xr[j][7]);
      *(uint4*)(&Xs[b][kg * XKSTR + ((hf * 5 + j) * HCOLS + 1 + xi) * 16]) = cell;
    }
    if (tid < 160) {
      uint4 cell;
      cell.x = pack2(hr[0], hr[1]); cell.y = pack2(hr[2], hr[3]);
      cell.z = pack2(hr[4], hr[5]); cell.w = pack2(hr[6], hr[7]);
      *(uint4*)(&Xs[b][hkg * XKSTR + (hrr * HCOLS + (hside ? 33 : 0)) * 16]) = cell;
    }
  };

  // ---- prologue: stage tile 0 into buf 0 ----
  {
    const int ts = s * 9;
    LOADX(ts >> 6, ((ts >> 2) & 15) * 8, (ts & 3) * 32);
    WRITEX(0);
  }
  __syncthreads();   // drains Ws DMA + Xs writes (full drain OK once)

  f32x16 acc[2];
  acc[0] = (f32x16)(0.f); acc[1] = (f32x16)(0.f);

  #pragma unroll 1
  for (int i = 0; i < 9; ++i) {
    const int cts  = s * 9 + i;
    const int cimg = cts >> 6;
    const int cgy0 = ((cts >> 2) & 15) * 8;
    const int cgx0 = (cts & 3) * 32;
    const unsigned char* xb = Xs[i & 1];

    if (i < 8) {   // T14: issue next tile's loads; consumed by WRITEX after compute
      const int nts = cts + 1;
      LOADX(nts >> 6, ((nts >> 2) & 15) * 8, (nts & 3) * 32);
    }

    // ---- compute: 9 taps from buf[i&1] ----
    #pragma unroll
    for (int t = 0; t < 9; ++t) {
      const int dy = (t >= 6) ? 2 : (t >= 3 ? 1 : 0);
      const int dx = t - dy * 3;
      int boff[2];
      #pragma unroll
      for (int nf = 0; nf < 2; ++nf)
        boff[nf] = lkh * XKSTR + ((wn * 2 + nf + dy) * HCOLS + dx + lpx) * 16;
      const int aoff = t * 8192 + lkh * 1024 + (wm * 32 + lpx) * 16;
      #pragma unroll
      for (int ks = 0; ks < 4; ++ks) {
        bf16x8 A  = *(const bf16x8*)&Ws[aoff + ks * 2048];
        bf16x8 B0 = *(const bf16x8*)&xb[boff[0] + ks * 2 * XKSTR];
        bf16x8 B1 = *(const bf16x8*)&xb[boff[1] + ks * 2 * XKSTR];
        acc[0] = __builtin_amdgcn_mfma_f32_32x32x16_bf16(A, B0, acc[0], 0, 0, 0);
        acc[1] = __builtin_amdgcn_mfma_f32_32x32x16_bf16(A, B1, acc[1], 0, 0, 0);
      }
    }

    // ---- stores: issued, NOT drained (overlap next tile) ----
    #pragma unroll
    for (int nf = 0; nf < 2; ++nf) {
      const int y = cgy0 + wn * 2 + nf;
      float* op = out + (size_t)cimg * C_OUT * HW + (size_t)y * Wimg + cgx0 + lpx;
      #pragma unroll
      for (int r = 0; r < 16; ++r) {
        const int co = coh * 64 + wm * 32 + (r & 3) + 8 * (r >> 2) + lkh * 4;
        op[(size_t)co * HW] = acc[nf][r] + ((const float*)&bq[r >> 2])[r & 3];
      }
    }
    acc[0] = (f32x16)(0.f); acc[1] = (f32x16)(0.f);

    if (i < 8) {
      // write NEXT tile into the OTHER buffer — concurrent with slow waves' compute(i)
      WRITEX((i + 1) & 1);
      // single barrier per tile: publish buf[(i+1)&1]; stores stay in flight
      asm volatile("s_waitcnt lgkmcnt(0)" ::: "memory");
      __builtin_amdgcn_s_barrier();
      __builtin_amdgcn_sched_barrier(0);
    }
  }
}

extern "C" void kernel_launch(void* const* d_in, const int* in_sizes, int n_in,
                              void* d_out, int out_size, void* d_ws, size_t ws_size,
                              hipStream_t stream) {
  const float* x    = (const float*)d_in[0];
  const float* w    = (const float*)d_in[1];
  const float* bias = (const float*)d_in[2];
  float* out = (float*)d_out;
  unsigned short* wt = (unsigned short*)d_ws;  // 147456 B

  wt_transform<<<(9 * C_OUT * C_IN + 255) / 256, 256, 0, stream>>>(w, wt);

  conv_mfma<<<dim3(512), 512, 0, stream>>>(x, wt, bias, out);
}